// Round 2
// baseline (138.528 us; speedup 1.0000x reference)
//
#include <hip/hip_runtime.h>
#include <cstdint>
#include <cstddef>

#define N_PTS 4096
#define KDIM  512
#define NFEAT 5
#define GRID_BLKS 512

typedef __attribute__((ext_vector_type(8))) short bf16x8;   // 8 bf16 = 4 VGPRs
typedef __attribute__((ext_vector_type(4))) float f32x4;
typedef uint32_t u32;

// round-to-nearest-even fp32 -> bf16 (inputs finite)
__device__ inline unsigned short f2bf(float f) {
  union { float f; u32 u; } v; v.f = f;
  u32 r = (v.u + 0x7fffu + ((v.u >> 16) & 1u)) >> 16;
  return (unsigned short)r;
}

// async global->LDS, 16B per lane (dest is wave-uniform base + lane*16)
__device__ inline void load_lds16(const void* g, void* l) {
  __builtin_amdgcn_global_load_lds(
      (const __attribute__((address_space(1))) void*)g,
      (__attribute__((address_space(3))) void*)l, 16, 0, 0);
}

// ---------------------------------------------------------------------------
// Kernel 1: X (fp32) -> bf16 + per-row squared norms; zeroes gsum + barrier
// ---------------------------------------------------------------------------
__global__ __launch_bounds__(256) void prep_kernel(const float* __restrict__ X,
                                                   short* __restrict__ Xb,
                                                   float* __restrict__ sq,
                                                   float* __restrict__ gsum,
                                                   u32* __restrict__ bct) {
  if (blockIdx.x == 0 && threadIdx.x == 0) { *gsum = 0.f; *bct = 0u; }
  const int row = blockIdx.x;
  const int t = threadIdx.x;
  const float2 v = ((const float2*)(X + (size_t)row * KDIM))[t];
  short2 b;
  b.x = (short)f2bf(v.x);
  b.y = (short)f2bf(v.y);
  ((short2*)(Xb + (size_t)row * KDIM))[t] = b;
  float s = v.x * v.x + v.y * v.y;
#pragma unroll
  for (int off = 32; off; off >>= 1) s += __shfl_down(s, off);
  __shared__ float ws[4];
  if ((t & 63) == 0) ws[t >> 6] = s;
  __syncthreads();
  if (t == 0) sq[row] = ws[0] + ws[1] + ws[2] + ws[3];
}

// ---------------------------------------------------------------------------
// Kernel 2 (FUSED): 512 blocks x 2 tiles of 128x128. GEMM -> fp32 distances
// in accumulator registers -> block distance-sum -> MANUAL grid barrier
// (arrive-and-wait on device-scope atomics; all 512 blocks co-resident:
// 32.8KB LDS < 160/4, __launch_bounds__(256,2) caps VGPR at 256 -> 2
// blocks/CU guaranteed, grid == capacity) -> 5-way exp -> fp32 out.
// No Dw intermediate, no bf16 roundtrip of d, no tail.
// ---------------------------------------------------------------------------
__global__ __launch_bounds__(256, 2) void fused_kernel(
    const short* __restrict__ Xb, const float* __restrict__ sq,
    const float* __restrict__ mult, float* __restrict__ gsum,
    u32* __restrict__ bct, float* __restrict__ out) {
  __shared__ short As[128 * 64];   // 16 KB
  __shared__ short Bs[128 * 64];   // 16 KB
  __shared__ float red[4];

  const int tid = threadIdx.x;
  const int lane = tid & 63;
  const int wid = tid >> 6;
  const int wave_m = wid >> 1, wave_n = wid & 1;
  const int lhi = lane >> 4, llo = lane & 15;

  // staging: lane t fetches row (t>>3), k-granule (t&7)^(row&7) -> LDS slot t
  const int srow = tid >> 3;                 // 0..31
  const int sgran = (tid & 7) ^ (srow & 7);  // XOR-swizzled granule

  f32x4 acc[2][4][4];   // tt index is compile-time (tt-loops fully unrolled)
  float lsum = 0.f;

#pragma unroll
  for (int tt = 0; tt < 2; ++tt) {
    const int t = (int)blockIdx.x + tt * GRID_BLKS;
    const int bm = t >> 5, bn = t & 31;

#pragma unroll
    for (int i = 0; i < 4; ++i)
#pragma unroll
      for (int j = 0; j < 4; ++j) acc[tt][i][j] = (f32x4){0.f, 0.f, 0.f, 0.f};

    const size_t ga0 = (size_t)(bm * 128 + srow) * KDIM + sgran * 8;
    const size_t gb0 = (size_t)(bn * 128 + srow) * KDIM + sgran * 8;

    for (int kt = 0; kt < KDIM / 64; ++kt) {
      const int koff = kt * 64;
#pragma unroll
      for (int g = 0; g < 4; ++g) {
        load_lds16(Xb + ga0 + (size_t)g * 32 * KDIM + koff,
                   (char*)As + g * 4096 + tid * 16);
        load_lds16(Xb + gb0 + (size_t)g * 32 * KDIM + koff,
                   (char*)Bs + g * 4096 + tid * 16);
      }
      __syncthreads();

#pragma unroll
      for (int h = 0; h < 2; ++h) {
        bf16x8 a[4], b[4];
#pragma unroll
        for (int i = 0; i < 4; ++i) {
          const int ra = wave_m * 64 + i * 16 + llo;
          const int rb = wave_n * 64 + i * 16 + llo;
          const int c = h * 4 + lhi;
          a[i] = *(const bf16x8*)&As[ra * 64 + ((c ^ (ra & 7)) << 3)];
          b[i] = *(const bf16x8*)&Bs[rb * 64 + ((c ^ (rb & 7)) << 3)];
        }
#pragma unroll
        for (int i = 0; i < 4; ++i)
#pragma unroll
          for (int j = 0; j < 4; ++j)
            acc[tt][i][j] = __builtin_amdgcn_mfma_f32_16x16x32_bf16(
                a[i], b[j], acc[tt][i][j], 0, 0, 0);
      }
      __syncthreads();
    }

    // epilogue: C/D layout col=lane&15, row=(lane>>4)*4+reg
    // d = sqrt(max(sqi+sqj-2*dot, 0)), exact-zero diagonal; store d in place
    const int gi0 = bm * 128, gj0 = bn * 128;
    const int r_base = wave_m * 64 + lhi * 4;
    const int c_base = wave_n * 64 + llo;
    float sqj[4];
#pragma unroll
    for (int j = 0; j < 4; ++j) sqj[j] = sq[gj0 + c_base + j * 16];
#pragma unroll
    for (int i = 0; i < 4; ++i) {
#pragma unroll
      for (int rr = 0; rr < 4; ++rr) {
        const int r = r_base + i * 16 + rr;
        const float sqi = sq[gi0 + r];
#pragma unroll
        for (int j = 0; j < 4; ++j) {
          const int c = c_base + j * 16;
          float d2 = sqi + sqj[j] - 2.f * acc[tt][i][j][rr];
          float dd = sqrtf(fmaxf(d2, 0.f));
          if (gi0 + r == gj0 + c) dd = 0.f;  // exact-zero diagonal
          lsum += dd;
          acc[tt][i][j][rr] = dd;
        }
      }
    }
  }

  // block partial sum -> gsum (one device-scope atomic per block)
#pragma unroll
  for (int off = 32; off; off >>= 1) lsum += __shfl_down(lsum, off);
  if (lane == 0) red[wid] = lsum;
  __syncthreads();

  // ---- manual grid-wide barrier: arrive-and-wait ----
  if (tid == 0) {
    atomicAdd(gsum, red[0] + red[1] + red[2] + red[3]);  // device-scope
    __hip_atomic_fetch_add(bct, 1u, __ATOMIC_ACQ_REL,
                           __HIP_MEMORY_SCOPE_AGENT);
    while (__hip_atomic_load(bct, __ATOMIC_ACQUIRE,
                             __HIP_MEMORY_SCOPE_AGENT) < (u32)GRID_BLKS) {
      __builtin_amdgcn_s_sleep(8);
    }
  }
  __syncthreads();

  // agent-scope load bypasses L1 (per-CU L1 not coherent)
  const float gs =
      __hip_atomic_load(gsum, __ATOMIC_RELAXED, __HIP_MEMORY_SCOPE_AGENT);
  const float bw = gs * (1.0f / ((float)N_PTS * (float)(N_PTS - 1)));
  float cf[NFEAT];
#pragma unroll
  for (int f = 0; f < NFEAT; ++f) cf[f] = -1.0f / (bw * mult[f]);

  // phase 2: 5-way exp on register-resident distances, direct fp32 stores
#pragma unroll
  for (int tt = 0; tt < 2; ++tt) {
    const int t = (int)blockIdx.x + tt * GRID_BLKS;
    const int bm = t >> 5, bn = t & 31;
    const int gi0 = bm * 128 + wave_m * 64 + lhi * 4;
    const int gj0 = bn * 128 + wave_n * 64 + llo;
#pragma unroll
    for (int i = 0; i < 4; ++i) {
#pragma unroll
      for (int rr = 0; rr < 4; ++rr) {
        float* orow = out + (size_t)(gi0 + i * 16 + rr) * N_PTS + gj0;
#pragma unroll
        for (int j = 0; j < 4; ++j) {
          const float d = acc[tt][i][j][rr];
          float a = 0.f;
#pragma unroll
          for (int f = 0; f < NFEAT; ++f) a += __expf(d * cf[f]);
          orow[j * 16] = a;
        }
      }
    }
  }
}

extern "C" void kernel_launch(void* const* d_in, const int* in_sizes, int n_in,
                              void* d_out, int out_size, void* d_ws, size_t ws_size,
                              hipStream_t stream) {
  const float* X = (const float*)d_in[0];
  const float* mult = (const float*)d_in[1];
  float* out = (float*)d_out;

  // ws: gsum@0 | barrier@256 | sq@1024 (16KB) | Xb@17408 (4MB)
  char* ws = (char*)d_ws;
  float* gsum = (float*)ws;
  u32* bct = (u32*)(ws + 256);
  float* sq = (float*)(ws + 1024);
  short* Xb = (short*)(ws + 1024 + N_PTS * sizeof(float));

  prep_kernel<<<N_PTS, 256, 0, stream>>>(X, Xb, sq, gsum, bct);
  fused_kernel<<<GRID_BLKS, 256, 0, stream>>>(Xb, sq, mult, gsum, bct, out);
}

// Round 4
// 130.993 us; speedup vs baseline: 1.0575x; 1.0575x over previous
//
#include <hip/hip_runtime.h>
#include <cstdint>
#include <cstddef>

#define N_PTS 4096
#define KDIM  512
#define NFEAT 5

typedef __attribute__((ext_vector_type(8))) short bf16x8;   // 8 bf16 = 4 VGPRs
typedef __attribute__((ext_vector_type(4))) float f32x4;
typedef uint32_t u32;

// round-to-nearest-even fp32 -> bf16 (inputs finite)
__device__ inline unsigned short f2bf(float f) {
  union { float f; u32 u; } v; v.f = f;
  u32 r = (v.u + 0x7fffu + ((v.u >> 16) & 1u)) >> 16;
  return (unsigned short)r;
}

// async global->LDS, 16B per lane (dest is wave-uniform base + lane*16)
__device__ inline void load_lds16(const void* g, void* l) {
  __builtin_amdgcn_global_load_lds(
      (const __attribute__((address_space(1))) void*)g,
      (__attribute__((address_space(3))) void*)l, 16, 0, 0);
}

// ---------------------------------------------------------------------------
// Kernel 1: X (fp32) -> bf16 + per-row squared norms; zeroes gsum
// ---------------------------------------------------------------------------
__global__ __launch_bounds__(256) void prep_kernel(const float* __restrict__ X,
                                                   short* __restrict__ Xb,
                                                   float* __restrict__ sq,
                                                   float* __restrict__ gsum) {
  if (blockIdx.x == 0 && threadIdx.x == 0) *gsum = 0.f;
  const int row = blockIdx.x;
  const int t = threadIdx.x;
  const float2 v = ((const float2*)(X + (size_t)row * KDIM))[t];
  short2 b;
  b.x = (short)f2bf(v.x);
  b.y = (short)f2bf(v.y);
  ((short2*)(Xb + (size_t)row * KDIM))[t] = b;
  float s = v.x * v.x + v.y * v.y;
#pragma unroll
  for (int off = 32; off; off >>= 1) s += __shfl_down(s, off);
  __shared__ float ws[4];
  if ((t & 63) == 0) ws[t >> 6] = s;
  __syncthreads();
  if (t == 0) sq[row] = ws[0] + ws[1] + ws[2] + ws[3];
}

// ---------------------------------------------------------------------------
// Shared GEMM tile body (128x128, BK=64, XOR-swizzled LDS, width-16
// global_load_lds). Computes acc[i][j] = dot(x_r, x_c) fragments.
// Proven correct in rounds 0/2 (absmax 0.015625).
// ---------------------------------------------------------------------------
#define GEMM_TILE(bm, bn, acc, As, Bs)                                        \
  {                                                                           \
    const size_t ga0 = (size_t)((bm)*128 + srow) * KDIM + sgran * 8;          \
    const size_t gb0 = (size_t)((bn)*128 + srow) * KDIM + sgran * 8;          \
    for (int kt = 0; kt < KDIM / 64; ++kt) {                                  \
      const int koff = kt * 64;                                               \
      _Pragma("unroll") for (int g = 0; g < 4; ++g) {                         \
        load_lds16(Xb + ga0 + (size_t)g * 32 * KDIM + koff,                   \
                   (char*)As + g * 4096 + tid * 16);                          \
        load_lds16(Xb + gb0 + (size_t)g * 32 * KDIM + koff,                   \
                   (char*)Bs + g * 4096 + tid * 16);                          \
      }                                                                       \
      __syncthreads();                                                        \
      _Pragma("unroll") for (int h = 0; h < 2; ++h) {                         \
        bf16x8 a[4], b[4];                                                    \
        _Pragma("unroll") for (int i = 0; i < 4; ++i) {                       \
          const int ra = wave_m * 64 + i * 16 + llo;                          \
          const int rb = wave_n * 64 + i * 16 + llo;                          \
          const int c = h * 4 + lhi;                                          \
          a[i] = *(const bf16x8*)&As[ra * 64 + ((c ^ (ra & 7)) << 3)];        \
          b[i] = *(const bf16x8*)&Bs[rb * 64 + ((c ^ (rb & 7)) << 3)];        \
        }                                                                     \
        _Pragma("unroll") for (int i = 0; i < 4; ++i)                         \
            _Pragma("unroll") for (int j = 0; j < 4; ++j)                     \
                acc[i][j] = __builtin_amdgcn_mfma_f32_16x16x32_bf16(          \
                    a[i], b[j], acc[i][j], 0, 0, 0);                          \
      }                                                                       \
      __syncthreads();                                                        \
    }                                                                         \
  }

// ---------------------------------------------------------------------------
// Kernel 2: distance-SUM only, upper-triangle tiles (528 blocks).
// Off-diagonal tiles weighted 2x (symmetry; d_ij == d_ji bitwise since the
// bf16 dot is the same k-ordered MFMA chain). No stores, no barrier.
// ---------------------------------------------------------------------------
__global__ __launch_bounds__(256, 2) void sum_kernel(
    const short* __restrict__ Xb, const float* __restrict__ sq,
    float* __restrict__ gsum) {
  __shared__ short As[128 * 64];   // 16 KB
  __shared__ short Bs[128 * 64];   // 16 KB
  __shared__ float red[4];

  const int tid = threadIdx.x;
  const int lane = tid & 63;
  const int wid = tid >> 6;
  const int wave_m = wid >> 1, wave_n = wid & 1;
  const int lhi = lane >> 4, llo = lane & 15;
  const int srow = tid >> 3;
  const int sgran = (tid & 7) ^ (srow & 7);

  // triangular decode: block -> (bm, bn) with bm <= bn
  int t = (int)blockIdx.x;
  int bm = 0;
  while (t >= 32 - bm) { t -= 32 - bm; ++bm; }
  const int bn = bm + t;

  f32x4 acc[4][4];
#pragma unroll
  for (int i = 0; i < 4; ++i)
#pragma unroll
    for (int j = 0; j < 4; ++j) acc[i][j] = (f32x4){0.f, 0.f, 0.f, 0.f};

  GEMM_TILE(bm, bn, acc, As, Bs);

  // epilogue: accumulate distances; zero the exact diagonal (bf16 dot noise)
  float lsum = 0.f;
  const int gi0 = bm * 128, gj0 = bn * 128;
  const int r_base = wave_m * 64 + lhi * 4;
  const int c_base = wave_n * 64 + llo;
  float sqj[4];
#pragma unroll
  for (int j = 0; j < 4; ++j) sqj[j] = sq[gj0 + c_base + j * 16];
#pragma unroll
  for (int i = 0; i < 4; ++i) {
#pragma unroll
    for (int rr = 0; rr < 4; ++rr) {
      const int r = r_base + i * 16 + rr;
      const float sqi = sq[gi0 + r];
#pragma unroll
      for (int j = 0; j < 4; ++j) {
        const int c = c_base + j * 16;            // local column 0..127
        const float d2 = sqi + sqj[j] - 2.f * acc[i][j][rr];
        float dd = sqrtf(fmaxf(d2, 0.f));
        if (gi0 + r == gj0 + c) dd = 0.f;         // global row == global col
        lsum += dd;
      }
    }
  }

#pragma unroll
  for (int off = 32; off; off >>= 1) lsum += __shfl_down(lsum, off);
  if (lane == 0) red[wid] = lsum;
  __syncthreads();
  if (tid == 0) {
    const float w = (bm == bn) ? 1.f : 2.f;
    atomicAdd(gsum, w * (red[0] + red[1] + red[2] + red[3]));
  }
}

// ---------------------------------------------------------------------------
// Kernel 3: recompute GEMM (full 1024 tiles) + 5-way exp + fp32 out.
// gsum is final by kernel-boundary ordering; no barrier, no reduction.
// ---------------------------------------------------------------------------
__global__ __launch_bounds__(256, 2) void rbf_kernel(
    const short* __restrict__ Xb, const float* __restrict__ sq,
    const float* __restrict__ mult, const float* __restrict__ gsum,
    float* __restrict__ out) {
  __shared__ short As[128 * 64];   // 16 KB
  __shared__ short Bs[128 * 64];   // 16 KB

  const int tid = threadIdx.x;
  const int lane = tid & 63;
  const int wid = tid >> 6;
  const int wave_m = wid >> 1, wave_n = wid & 1;
  const int lhi = lane >> 4, llo = lane & 15;
  const int srow = tid >> 3;
  const int sgran = (tid & 7) ^ (srow & 7);

  const int bm = blockIdx.y, bn = blockIdx.x;

  // load bw early (hides under GEMM)
  const float bw = *gsum * (1.0f / ((float)N_PTS * (float)(N_PTS - 1)));
  float cf[NFEAT];
#pragma unroll
  for (int f = 0; f < NFEAT; ++f) cf[f] = -1.0f / (bw * mult[f]);

  f32x4 acc[4][4];
#pragma unroll
  for (int i = 0; i < 4; ++i)
#pragma unroll
    for (int j = 0; j < 4; ++j) acc[i][j] = (f32x4){0.f, 0.f, 0.f, 0.f};

  GEMM_TILE(bm, bn, acc, As, Bs);

  // epilogue: d -> 5-way exp -> direct fp32 stores (LOCAL column index!)
  const int gi0 = bm * 128, gj0 = bn * 128;
  const int r_base = wave_m * 64 + lhi * 4;
  const int c_base = wave_n * 64 + llo;
  float sqj[4];
#pragma unroll
  for (int j = 0; j < 4; ++j) sqj[j] = sq[gj0 + c_base + j * 16];
#pragma unroll
  for (int i = 0; i < 4; ++i) {
#pragma unroll
    for (int rr = 0; rr < 4; ++rr) {
      const int r = r_base + i * 16 + rr;
      const float sqi = sq[gi0 + r];
      float* orow = out + (size_t)(gi0 + r) * N_PTS + gj0;
#pragma unroll
      for (int j = 0; j < 4; ++j) {
        const int c = c_base + j * 16;            // local column 0..127
        float d2 = sqi + sqj[j] - 2.f * acc[i][j][rr];
        float dd = sqrtf(fmaxf(d2, 0.f));
        if (gi0 + r == gj0 + c) dd = 0.f;         // exact-zero diagonal -> a=5
        float a = 0.f;
#pragma unroll
        for (int f = 0; f < NFEAT; ++f) a += __expf(dd * cf[f]);
        orow[c] = a;                              // local offset from orow
      }
    }
  }
}

extern "C" void kernel_launch(void* const* d_in, const int* in_sizes, int n_in,
                              void* d_out, int out_size, void* d_ws, size_t ws_size,
                              hipStream_t stream) {
  const float* X = (const float*)d_in[0];
  const float* mult = (const float*)d_in[1];
  float* out = (float*)d_out;

  // ws: gsum@0 | sq@1024 (16KB) | Xb@17408 (4MB)
  char* ws = (char*)d_ws;
  float* gsum = (float*)ws;
  float* sq = (float*)(ws + 1024);
  short* Xb = (short*)(ws + 1024 + N_PTS * sizeof(float));

  prep_kernel<<<N_PTS, 256, 0, stream>>>(X, Xb, sq, gsum);
  sum_kernel<<<528, 256, 0, stream>>>(Xb, sq, gsum);
  rbf_kernel<<<dim3(32, 32), 256, 0, stream>>>(Xb, sq, mult, gsum, out);
}

// Round 5
// 122.116 us; speedup vs baseline: 1.1344x; 1.0727x over previous
//
#include <hip/hip_runtime.h>
#include <cstdint>
#include <cstddef>

#define N_PTS 4096
#define KDIM  512
#define NFEAT 5
#define NTILES 528   // 32*33/2 upper-triangle 128x128 tiles

typedef __attribute__((ext_vector_type(8))) short bf16x8;   // 8 bf16 = 4 VGPRs
typedef __attribute__((ext_vector_type(4))) float f32x4;
typedef uint32_t u32;

// round-to-nearest-even fp32 -> bf16 (inputs finite)
__device__ inline unsigned short f2bf(float f) {
  union { float f; u32 u; } v; v.f = f;
  u32 r = (v.u + 0x7fffu + ((v.u >> 16) & 1u)) >> 16;
  return (unsigned short)r;
}

__device__ inline void bf2f2(u32 u, float& a, float& b) {
  union { u32 u; float f; } x, y;
  x.u = u << 16; y.u = u & 0xffff0000u;
  a = x.f; b = y.f;
}

// async global->LDS, 16B per lane (dest is wave-uniform base + lane*16)
__device__ inline void load_lds16(const void* g, void* l) {
  __builtin_amdgcn_global_load_lds(
      (const __attribute__((address_space(1))) void*)g,
      (__attribute__((address_space(3))) void*)l, 16, 0, 0);
}

// ---------------------------------------------------------------------------
// Kernel 1: X (fp32) -> bf16 + per-row squared norms; zeroes gsum
// ---------------------------------------------------------------------------
__global__ __launch_bounds__(256) void prep_kernel(const float* __restrict__ X,
                                                   short* __restrict__ Xb,
                                                   float* __restrict__ sq,
                                                   float* __restrict__ gsum) {
  if (blockIdx.x == 0 && threadIdx.x == 0) *gsum = 0.f;
  const int row = blockIdx.x;
  const int t = threadIdx.x;
  const float2 v = ((const float2*)(X + (size_t)row * KDIM))[t];
  short2 b;
  b.x = (short)f2bf(v.x);
  b.y = (short)f2bf(v.y);
  ((short2*)(Xb + (size_t)row * KDIM))[t] = b;
  float s = v.x * v.x + v.y * v.y;
#pragma unroll
  for (int off = 32; off; off >>= 1) s += __shfl_down(s, off);
  __shared__ float ws[4];
  if ((t & 63) == 0) ws[t >> 6] = s;
  __syncthreads();
  if (t == 0) sq[row] = ws[0] + ws[1] + ws[2] + ws[3];
}

// ---------------------------------------------------------------------------
// Shared GEMM tile body (128x128, BK=64, XOR-swizzled LDS, width-16
// global_load_lds). acc[i][j] = dot fragments. Verified rounds 0/2/4.
// ---------------------------------------------------------------------------
#define GEMM_TILE(bm, bn, acc, As, Bs)                                        \
  {                                                                           \
    const size_t ga0 = (size_t)((bm)*128 + srow) * KDIM + sgran * 8;          \
    const size_t gb0 = (size_t)((bn)*128 + srow) * KDIM + sgran * 8;          \
    for (int kt = 0; kt < KDIM / 64; ++kt) {                                  \
      const int koff = kt * 64;                                               \
      _Pragma("unroll") for (int g = 0; g < 4; ++g) {                         \
        load_lds16(Xb + ga0 + (size_t)g * 32 * KDIM + koff,                   \
                   (char*)As + g * 4096 + tid * 16);                          \
        load_lds16(Xb + gb0 + (size_t)g * 32 * KDIM + koff,                   \
                   (char*)Bs + g * 4096 + tid * 16);                          \
      }                                                                       \
      __syncthreads();                                                        \
      _Pragma("unroll") for (int h = 0; h < 2; ++h) {                         \
        bf16x8 a[4], b[4];                                                    \
        _Pragma("unroll") for (int i = 0; i < 4; ++i) {                       \
          const int ra = wave_m * 64 + i * 16 + llo;                          \
          const int rb = wave_n * 64 + i * 16 + llo;                          \
          const int c = h * 4 + lhi;                                          \
          a[i] = *(const bf16x8*)&As[ra * 64 + ((c ^ (ra & 7)) << 3)];        \
          b[i] = *(const bf16x8*)&Bs[rb * 64 + ((c ^ (rb & 7)) << 3)];        \
        }                                                                     \
        _Pragma("unroll") for (int i = 0; i < 4; ++i)                         \
            _Pragma("unroll") for (int j = 0; j < 4; ++j)                     \
                acc[i][j] = __builtin_amdgcn_mfma_f32_16x16x32_bf16(          \
                    a[i], b[j], acc[i][j], 0, 0, 0);                          \
      }                                                                       \
      __syncthreads();                                                        \
    }                                                                         \
  }

// ---------------------------------------------------------------------------
// Kernel 2: upper-triangle tiles (528 blocks): GEMM -> fp32 d -> weighted
// distance sum (w=2 off-diag) AND bf16 fragment-ordered Dw store (17.3 MB).
// Dw layout: [triangle_tile][wid][i][half][lane][8 bf16]  (baseline-verified)
// ---------------------------------------------------------------------------
__global__ __launch_bounds__(256, 2) void dist_kernel(
    const short* __restrict__ Xb, const float* __restrict__ sq,
    unsigned short* __restrict__ Dw, float* __restrict__ gsum) {
  __shared__ short As[128 * 64];   // 16 KB
  __shared__ short Bs[128 * 64];   // 16 KB
  __shared__ float red[4];

  const int tid = threadIdx.x;
  const int lane = tid & 63;
  const int wid = tid >> 6;
  const int wave_m = wid >> 1, wave_n = wid & 1;
  const int lhi = lane >> 4, llo = lane & 15;
  const int srow = tid >> 3;
  const int sgran = (tid & 7) ^ (srow & 7);

  // triangular decode: block -> (bm, bn) with bm <= bn
  int t = (int)blockIdx.x;
  int bm = 0;
  while (t >= 32 - bm) { t -= 32 - bm; ++bm; }
  const int bn = bm + t;

  f32x4 acc[4][4];
#pragma unroll
  for (int i = 0; i < 4; ++i)
#pragma unroll
    for (int j = 0; j < 4; ++j) acc[i][j] = (f32x4){0.f, 0.f, 0.f, 0.f};

  GEMM_TILE(bm, bn, acc, As, Bs);

  // epilogue: d, diag zero, sum, bf16 pack + dense fragment-ordered store
  float lsum = 0.f;
  const int gi0 = bm * 128, gj0 = bn * 128;
  const int r_base = wave_m * 64 + lhi * 4;
  const int c_base = wave_n * 64 + llo;
  float sqj[4];
#pragma unroll
  for (int j = 0; j < 4; ++j) sqj[j] = sq[gj0 + c_base + j * 16];

  const size_t tile_base =
      (size_t)blockIdx.x * 16384 + (size_t)wid * 4096;

#pragma unroll
  for (int i = 0; i < 4; ++i) {
    union { unsigned short s[16]; uint4 q[2]; } pk;
#pragma unroll
    for (int rr = 0; rr < 4; ++rr) {
      const int r = r_base + i * 16 + rr;
      const float sqi = sq[gi0 + r];
#pragma unroll
      for (int j = 0; j < 4; ++j) {
        const int c = c_base + j * 16;            // local column
        float d2 = sqi + sqj[j] - 2.f * acc[i][j][rr];
        float dd = sqrtf(fmaxf(d2, 0.f));
        if (gi0 + r == gj0 + c) dd = 0.f;         // exact-zero diagonal
        lsum += dd;
        pk.s[rr * 4 + j] = f2bf(dd);
      }
    }
    unsigned short* dst = Dw + tile_base + (size_t)i * 1024;
    *(uint4*)(dst + lane * 8) = pk.q[0];
    *(uint4*)(dst + 512 + lane * 8) = pk.q[1];
  }

#pragma unroll
  for (int off = 32; off; off >>= 1) lsum += __shfl_down(lsum, off);
  if (lane == 0) red[wid] = lsum;
  __syncthreads();
  if (tid == 0) {
    const float w = (bm == bn) ? 1.f : 2.f;
    atomicAdd(gsum, w * (red[0] + red[1] + red[2] + red[3]));
  }
}

// ---------------------------------------------------------------------------
// Kernel 3: 528 blocks. Load Dw tile (dense), RBF once per unordered pair:
//  - fast path (mult == {.25,.5,1,2,4}): t=exp(-d/bw); sum = t^4+t^2+t+
//    sqrt(t)+sqrt(sqrt(t))  (3 transcendentals instead of 5)
//  - normal (r,c) store direct; mirror (c,r) via padded-LDS transpose,
//    4x float4 (64B contiguous) per thread. Diagonal tiles skip mirror.
// ---------------------------------------------------------------------------
__global__ __launch_bounds__(256) void rbf_kernel(
    const unsigned short* __restrict__ Dw, const float* __restrict__ gsum,
    const float* __restrict__ mult, float* __restrict__ out) {
  __shared__ float T[32 * 132];   // padded: stride 132 -> 2-way banks (free)

  const int tid = threadIdx.x;
  const int lane = tid & 63;
  const int wid = tid >> 6;
  const int wave_m = wid >> 1, wave_n = wid & 1;
  const int lhi = lane >> 4, llo = lane & 15;

  // triangular decode: block -> (bm, bn) with bm <= bn
  int t = (int)blockIdx.x;
  int bm = 0;
  while (t >= 32 - bm) { t -= 32 - bm; ++bm; }
  const int bn = bm + t;
  const bool diag = (bm == bn);

  const float bw = *gsum * (1.0f / ((float)N_PTS * (float)(N_PTS - 1)));
  const float m0 = mult[0], m1 = mult[1], m2 = mult[2], m3 = mult[3],
              m4 = mult[4];
  const bool fast = (m0 == 0.25f && m1 == 0.5f && m2 == 1.0f && m3 == 2.0f &&
                     m4 == 4.0f);
  const float c1 = -1.0f / (bw * m2);   // base coefficient (mult==1)
  float cf[NFEAT];
  cf[0] = -1.0f / (bw * m0); cf[1] = -1.0f / (bw * m1); cf[2] = c1;
  cf[3] = -1.0f / (bw * m3); cf[4] = -1.0f / (bw * m4);

  const size_t tile_base =
      (size_t)blockIdx.x * 16384 + (size_t)wid * 4096;

  // load all fragments upfront (hide VMEM latency under exp)
  uint4 q[4][2];
#pragma unroll
  for (int i = 0; i < 4; ++i) {
    const unsigned short* src = Dw + tile_base + (size_t)i * 1024;
    q[i][0] = *(const uint4*)(src + lane * 8);
    q[i][1] = *(const uint4*)(src + 512 + lane * 8);
  }

  const int gi0 = bm * 128, gj0 = bn * 128;
  const int r_off = wave_m * 64 + lhi * 4;   // + i*16 + rr
  const int c_off = wave_n * 64 + llo;       // + j*16

#pragma unroll
  for (int i = 0; i < 4; ++i) {
    float v[16];
    bf2f2(q[i][0].x, v[0], v[1]);   bf2f2(q[i][0].y, v[2], v[3]);
    bf2f2(q[i][0].z, v[4], v[5]);   bf2f2(q[i][0].w, v[6], v[7]);
    bf2f2(q[i][1].x, v[8], v[9]);   bf2f2(q[i][1].y, v[10], v[11]);
    bf2f2(q[i][1].z, v[12], v[13]); bf2f2(q[i][1].w, v[14], v[15]);

    float o[16];
    if (fast) {
#pragma unroll
      for (int e = 0; e < 16; ++e) {
        const float tt = __expf(v[e] * c1);       // t = exp(-d/bw)
        const float t2 = tt * tt;
        const float t4 = t2 * t2;
        const float s = sqrtf(tt);                // t^(1/2)
        const float qq = sqrtf(s);                // t^(1/4)
        o[e] = t4 + t2 + tt + s + qq;             // diag: d=0 -> exactly 5
      }
    } else {
#pragma unroll
      for (int e = 0; e < 16; ++e) {
        float a = 0.f;
#pragma unroll
        for (int f = 0; f < NFEAT; ++f) a += __expf(v[e] * cf[f]);
        o[e] = a;
      }
    }

    // normal (r,c) store
#pragma unroll
    for (int rr = 0; rr < 4; ++rr) {
      float* orow = out + (size_t)(gi0 + r_off + i * 16 + rr) * N_PTS + gj0;
#pragma unroll
      for (int j = 0; j < 4; ++j) orow[c_off + j * 16] = o[rr * 4 + j];
    }

    // mirror (c,r) store via LDS transpose (skip on diagonal tiles)
    if (!diag) {
#pragma unroll
      for (int rr = 0; rr < 4; ++rr)
#pragma unroll
        for (int j = 0; j < 4; ++j)
          T[(wave_m * 16 + lhi * 4 + rr) * 132 + wave_n * 64 + j * 16 + llo] =
              o[rr * 4 + j];
      __syncthreads();
      // thread -> (c = tid>>1, row-group g = tid&1); 16 consecutive floats
      const int c = tid >> 1;
      const int g = tid & 1;
      float w[16];
#pragma unroll
      for (int k = 0; k < 16; ++k) w[k] = T[(g * 16 + k) * 132 + c];
      float* mrow =
          out + (size_t)(gj0 + c) * N_PTS + gi0 + g * 64 + i * 16;
      *(float4*)(mrow + 0) = (float4){w[0], w[1], w[2], w[3]};
      *(float4*)(mrow + 4) = (float4){w[4], w[5], w[6], w[7]};
      *(float4*)(mrow + 8) = (float4){w[8], w[9], w[10], w[11]};
      *(float4*)(mrow + 12) = (float4){w[12], w[13], w[14], w[15]};
      __syncthreads();   // T reused next i
    }
  }
}

extern "C" void kernel_launch(void* const* d_in, const int* in_sizes, int n_in,
                              void* d_out, int out_size, void* d_ws, size_t ws_size,
                              hipStream_t stream) {
  const float* X = (const float*)d_in[0];
  const float* mult = (const float*)d_in[1];
  float* out = (float*)d_out;

  // ws: gsum@0 | sq@1024 (16KB) | Xb@17408 (4MB) | Dw@4211712 (17.3MB bf16)
  char* ws = (char*)d_ws;
  float* gsum = (float*)ws;
  float* sq = (float*)(ws + 1024);
  short* Xb = (short*)(ws + 1024 + N_PTS * sizeof(float));
  unsigned short* Dw = (unsigned short*)(ws + 1024 + N_PTS * sizeof(float) +
                                         (size_t)N_PTS * KDIM * sizeof(short));

  prep_kernel<<<N_PTS, 256, 0, stream>>>(X, Xb, sq, gsum);
  dist_kernel<<<NTILES, 256, 0, stream>>>(Xb, sq, Dw, gsum);
  rbf_kernel<<<NTILES, 256, 0, stream>>>(Dw, gsum, mult, out);
}